// Round 2
// baseline (124.885 us; speedup 1.0000x reference)
//
#include <hip/hip_runtime.h>

// AlignOnlySubLayer: out[b,m,d] = main[b,m,d] - sum_c softmax_m(C·M^T)[c,m] * C[c,d]
// B=8, Lc=Lm=2048, D=128, fp32 in/out.
// Round-10: attend_fused goes BARRIER-FREE. R9 showed E-elimination was wall-
// neutral: attend was bound by per-window __syncthreads DMA drains at 2
// waves/SIMD, not by HBM. Operands are L2-resident (1.5 MB/batch), reuse is
// only 1-2x, so LDS staging is pure overhead: read av (Cbf) and tv (CtL)
// MFMA fragments DIRECTLY global->reg with identical swizzle math (R9-proven
// element mapping). No main-loop barriers; 256-thr blocks (4 waves = 4
// c-slices, m-tile 32); grid 512 = 2 blocks/CU; LDS 64 KB epilogue-only.
// XCD batch affinity: b = bid&7 -> each XCD's L2 serves one batch.
//   convert: Cbf/Mbf = bf16(ctx/main) swizzled; Lg = 0            (unchanged)
//   stats  : L[c] = sum_m exp(S-40) via atomics (XCD affinity added)
//   prep   : CtL[b,d,c] = bf16(C[b,c,d]/L[b,c]) transposed+swizzled (unchanged)
//   attend_fused: per c-window: S = mfma(Cbf-frag, Mbf-frag) swapped 32x32x16,
//     exp+pack in-reg, shfl_xor(32) half-exchange -> PV B-frag, PV A = CtL
//     rows direct from global. Zero E traffic, zero main-loop LDS.
// Swizzle (all bf16 tensors): 16B chunk pc = (lc&8)|((lc^row)&7) within
// 64-elem groups; reads XOR the chunk index with row&7.

#define BATCH 8
#define L_SEQ 2048
#define DD 128
#define SHIFT 40.0f
#define LDA 136   // fallback/prep padded stride

typedef __attribute__((ext_vector_type(8))) short bf16x8;
typedef __attribute__((ext_vector_type(4))) short bf16x4;
typedef __attribute__((ext_vector_type(4))) float f32x4;
typedef __attribute__((ext_vector_type(16))) float f32x16;
typedef __attribute__((ext_vector_type(4))) unsigned int uint4v;

__device__ __forceinline__ short f2bf(float f) {
    unsigned u = __builtin_bit_cast(unsigned, f);
    return (short)((u + 0x8000u) >> 16);
}

// Async global->LDS, 16 B per lane. LDS dest = wave-uniform base + lane*16.
__device__ __forceinline__ void gl2lds16(const short* g, short* l) {
    __builtin_amdgcn_global_load_lds(
        (const __attribute__((address_space(1))) unsigned int*)g,
        (__attribute__((address_space(3))) unsigned int*)l, 16, 0, 0);
}

// fp32 global (rows of 128) -> bf16 LDS tile, stride LDA (fallback path only).
template <int NT>
__device__ __forceinline__ void stage_tile(short* __restrict__ dst,
                                           const float* __restrict__ src,
                                           int nelts, int t) {
    for (int base = 0; base < nelts; base += NT * 8) {
        int flat = base + t * 8;
        const float4* p = (const float4*)(src + flat);
        float4 v0 = p[0];
        float4 v1 = p[1];
        bf16x8 s;
        s[0] = f2bf(v0.x); s[1] = f2bf(v0.y); s[2] = f2bf(v0.z); s[3] = f2bf(v0.w);
        s[4] = f2bf(v1.x); s[5] = f2bf(v1.y); s[6] = f2bf(v1.z); s[7] = f2bf(v1.w);
        int row = flat >> 7;
        int col = flat & 127;
        *(bf16x8*)&dst[row * LDA + col] = s;
    }
}

__global__ __launch_bounds__(256) void zero_kernel(float* __restrict__ p, int n) {
    int i = blockIdx.x * 256 + threadIdx.x;
    if (i < n) p[i] = 0.0f;
}

// ---------------------------------------------------------------------------
// Fast path
// ---------------------------------------------------------------------------

// grid = 2048 x 256: one 16B chunk per thread for C and M; also zeros Lg.
__global__ __launch_bounds__(256) void convert_kernel(const float* __restrict__ ctx,
                                                      const float* __restrict__ mn,
                                                      short* __restrict__ Cbf,
                                                      short* __restrict__ Mbf,
                                                      float* __restrict__ Lg) {
    int tid = blockIdx.x * 256 + threadIdx.x;
    if (tid < BATCH * L_SEQ) Lg[tid] = 0.0f;
    const int half = BATCH * L_SEQ * DD / 8;  // chunks per tensor
    int id = tid;
    const float* src;
    short* dst;
    if (id < half) { src = ctx; dst = Cbf; }
    else           { id -= half; src = mn; dst = Mbf; }
    int row = id >> 4;
    int lc = id & 15;
    const float4* p = (const float4*)(src + ((size_t)row << 7) + lc * 8);
    float4 v0 = p[0];
    float4 v1 = p[1];
    bf16x8 s;
    s[0] = f2bf(v0.x); s[1] = f2bf(v0.y); s[2] = f2bf(v0.z); s[3] = f2bf(v0.w);
    s[4] = f2bf(v1.x); s[5] = f2bf(v1.y); s[6] = f2bf(v1.z); s[7] = f2bf(v1.w);
    int pc = (lc & 8) | ((lc ^ row) & 7);  // swizzle low 3 chunk bits by row&7
    *(bf16x8*)&dst[((size_t)row << 7) + pc * 8] = s;
}

// grid = 512 blocks (b = bid&7 for XCD batch affinity), 256 thr (4 waves).
// LDS: Cs 32 KB + Ms dbuf 2x16 KB = 64 KB -> 2 blocks/CU (8 waves/CU).
__global__ __launch_bounds__(256, 2) void stats_kernel(const short* __restrict__ Cbf,
                                                       const short* __restrict__ Mbf,
                                                       float* __restrict__ Lg) {
    __shared__ short Cs[128 * 128];
    __shared__ short Ms[2][64 * 128];

    int bid = blockIdx.x;
    int b  = bid & 7;          // XCD affinity: all blocks of batch b on one XCD
    int r2 = bid >> 3;
    int mc = r2 & 3;
    int ct = r2 >> 2;
    int t = threadIdx.x;
    int w = t >> 6;
    int l = t & 63;
    int a15 = l & 15;
    int q = l >> 4;
    int h = a15 & 7;
    int cw = (w & 1) * 64;   // wave c-offset within the 128-c tile
    int mw = (w >> 1) * 32;  // wave m-offset within the 64-m step

    {   // issue Cs (once, 8 insts/wave) + Ms buf0 (step 0, 4 insts/wave)
        const short* gC = Cbf + ((size_t)(b * L_SEQ + ct * 128)) * DD;
        const short* gM = Mbf + ((size_t)(b * L_SEQ + mc * 512)) * DD;
        #pragma unroll
        for (int ii = 0; ii < 8; ++ii) {
            int inst = w * 8 + ii;
            gl2lds16(gC + inst * 512 + l * 8, Cs + inst * 512);
        }
        #pragma unroll
        for (int ii = 0; ii < 4; ++ii) {
            int inst = w * 4 + ii;
            gl2lds16(gM + inst * 512 + l * 8, Ms[0] + inst * 512);
        }
    }

    __syncthreads();  // drains Cs + Ms[0]

    {   // prefetch step-1 M into Ms[1]; disjoint from Cs/Ms[0], flies over hoist
        const short* gM = Mbf + ((size_t)(b * L_SEQ + mc * 512 + 64)) * DD;
        #pragma unroll
        for (int ii = 0; ii < 4; ++ii) {
            int inst = w * 4 + ii;
            gl2lds16(gM + inst * 512 + l * 8, Ms[1] + inst * 512);
        }
    }

    // Hoist invariant C A-fragments: af[ks][i], 16 ds_read_b128 -> 64 VGPRs.
    bf16x8 af[4][4];
    #pragma unroll
    for (int ks = 0; ks < 4; ++ks) {
        int aoff = ((ks * 4 + q) ^ h) * 8;
        #pragma unroll
        for (int i = 0; i < 4; ++i)
            af[ks][i] = *(const bf16x8*)&Cs[(cw + i * 16 + a15) * 128 + aoff];
    }

    float ls[4][4] = {};  // partial L for c = ct*128 + cw + i*16 + q*4 + r

    for (int ms = 0; ms < 8; ++ms) {
        int bp = ms & 1;
        if (ms > 0) {
            __syncthreads();  // drains DMA into Ms[bp] (issued at ms-1)
            if (ms < 7) {     // prefetch next step into the OTHER buffer
                const short* gM = Mbf + ((size_t)(b * L_SEQ + mc * 512 + (ms + 1) * 64)) * DD;
                #pragma unroll
                for (int ii = 0; ii < 4; ++ii) {
                    int inst = w * 4 + ii;
                    gl2lds16(gM + inst * 512 + l * 8, Ms[bp ^ 1] + inst * 512);
                }
            }
        }

        // D[c][m]: A = hoisted C frags (wave's 64 c), B = M rows (wave's 32 m).
        f32x4 acc[4][2];
        #pragma unroll
        for (int i = 0; i < 4; ++i)
            #pragma unroll
            for (int j = 0; j < 2; ++j) {
                f32x4 z = {0.f, 0.f, 0.f, 0.f};
                acc[i][j] = z;
            }
        #pragma unroll
        for (int ks = 0; ks < 4; ++ks) {
            int aoff = ((ks * 4 + q) ^ h) * 8;
            bf16x8 bv[2];
            #pragma unroll
            for (int j = 0; j < 2; ++j)
                bv[j] = *(const bf16x8*)&Ms[bp][(mw + j * 16 + a15) * 128 + aoff];
            #pragma unroll
            for (int i = 0; i < 4; ++i)
                #pragma unroll
                for (int j = 0; j < 2; ++j)
                    acc[i][j] = __builtin_amdgcn_mfma_f32_16x16x32_bf16(af[ks][i], bv[j], acc[i][j], 0, 0, 0);
        }

        #pragma unroll
        for (int j = 0; j < 2; ++j)
            #pragma unroll
            for (int i = 0; i < 4; ++i)
                #pragma unroll
                for (int r = 0; r < 4; ++r)
                    ls[i][r] += __expf(acc[i][j][r] - SHIFT);
    }

    // Reduce partial L over the 16 m-columns (lane bits 0..3), then atomics.
    #pragma unroll
    for (int i = 0; i < 4; ++i)
        #pragma unroll
        for (int r = 0; r < 4; ++r) {
            float v = ls[i][r];
            v += __shfl_xor(v, 1);
            v += __shfl_xor(v, 2);
            v += __shfl_xor(v, 4);
            v += __shfl_xor(v, 8);
            ls[i][r] = v;
        }
    if (a15 == 0) {
        #pragma unroll
        for (int i = 0; i < 4; ++i) {
            int c = ct * 128 + cw + i * 16 + q * 4;
            #pragma unroll
            for (int r = 0; r < 4; ++r)
                atomicAdd(&Lg[(size_t)b * L_SEQ + c + r], ls[i][r]);  // 8-way total contention
        }
    }
}

// grid = 8 b * 16 cc = 128 blocks, 256 thr. CtL[b][d][c] = bf16(C/L), swizzled by d&7.
__global__ __launch_bounds__(256) void prep_kernel(const float* __restrict__ ctx,
                                                   const float* __restrict__ Lg,
                                                   short* __restrict__ CtL) {
    __shared__ short Ts[128 * LDA];
    __shared__ float invLs[128];

    int b = blockIdx.x >> 4;
    int cc = blockIdx.x & 15;
    int t = threadIdx.x;

    if (t < 128) invLs[t] = 1.0f / Lg[(size_t)b * L_SEQ + cc * 128 + t];
    __syncthreads();

    const float* src = ctx + ((size_t)(b * L_SEQ + cc * 128)) * DD;
    #pragma unroll
    for (int i = 0; i < 8; ++i) {
        int flat = i * 2048 + t * 8;
        int r = flat >> 7;
        int c = flat & 127;
        const float4* p = (const float4*)(src + flat);
        float4 v0 = p[0];
        float4 v1 = p[1];
        float il = invLs[r];
        bf16x8 s;
        s[0] = f2bf(v0.x * il); s[1] = f2bf(v0.y * il); s[2] = f2bf(v0.z * il); s[3] = f2bf(v0.w * il);
        s[4] = f2bf(v1.x * il); s[5] = f2bf(v1.y * il); s[6] = f2bf(v1.z * il); s[7] = f2bf(v1.w * il);
        *(bf16x8*)&Ts[r * LDA + c] = s;
    }
    __syncthreads();

    int d = t >> 1;
    int ch = (t & 1) * 64;
    int key = d & 7;
    #pragma unroll
    for (int i = 0; i < 8; ++i) {
        int c = ch + i * 8;
        bf16x8 v;
        #pragma unroll
        for (int j = 0; j < 8; ++j) v[j] = Ts[(c + j) * LDA + d];
        int pc = cc * 16 + (ch >> 3) + (i ^ key);
        *(bf16x8*)&CtL[((size_t)(b * DD + d)) * L_SEQ + pc * 8] = v;
    }
}

// Fused recompute-attend, BARRIER-FREE main loop, all operands global->reg.
// grid = 8 b * 64 mtiles(32 m) = 512 blocks (b = bid&7: XCD batch affinity),
// 256 thr = 4 waves = 4 c-slices of each 128-c window. LDS 64 KB epilogue only
// -> 2 blocks/CU. Per window per wave: 8 tv loads (issued first, independent),
// 8 av loads + 8 S-MFMA, exp+pack+shfl, 8 PV-MFMA. No __syncthreads until the
// cross-wave epilogue reduction.
__global__ __launch_bounds__(256, 2) void attend_fused(const short* __restrict__ Cbf,
                                                       const short* __restrict__ Mbf,
                                                       const short* __restrict__ CtL,
                                                       const float* __restrict__ mn,
                                                       float* __restrict__ out) {
    __shared__ float red[4][4096];   // 64 KB: red[wave][d*32 + m]

    int bid = blockIdx.x;
    int b = bid & 7;           // XCD batch affinity (grid%8==0 -> bijective)
    int mtile = bid >> 3;      // 0..63
    int t = threadIdx.x;
    int w = t >> 6;            // 0..3 = ch (c-slice of the window)
    int l = t & 63;
    int la = l & 31;
    int hi = l >> 5;
    int ch = w;

    int m_glob = mtile * 32 + la;      // this lane's m (D col)
    int key7 = la & 7;                 // swizzle key for all row-indexed reads

    // Hoist M B-fragments: mf[ks] covers d = ks*16 + hi*8 + e. L2-resident.
    bf16x8 mf[8];
    {
        const short* mrow = Mbf + ((size_t)(b * L_SEQ + m_glob)) * DD;
        #pragma unroll
        for (int ks = 0; ks < 8; ++ks) {
            int lc = ks * 2 + hi;
            int pc = (lc & 8) | ((lc ^ key7) & 7);
            mf[ks] = *(const bf16x8*)&mrow[pc * 8];
        }
    }

    // Row bases: Cbf A-rows (c = cs*128 + ch*32 + la), CtL A-rows (d = dg*32+la).
    const short* gC = Cbf + ((size_t)(b * L_SEQ + ch * 32 + la)) * DD;
    const short* gT = CtL + ((size_t)(b * DD + la)) * L_SEQ;

    f32x16 o[4];
    #pragma unroll
    for (int dg = 0; dg < 4; ++dg)
        #pragma unroll
        for (int r = 0; r < 16; ++r) o[dg][r] = 0.0f;

    for (int cs = 0; cs < 16; ++cs) {
        const short* gCw = gC + (size_t)cs * 128 * DD;   // window A-row base
        const short* gTw = gT + cs * 128;                // window chunk base

        // tv loads first: independent of S, fly over the whole S+exp phase.
        bf16x8 tv[4][2];
        #pragma unroll
        for (int dg = 0; dg < 4; ++dg)
            #pragma unroll
            for (int ks2 = 0; ks2 < 2; ++ks2) {
                int lc2 = ch * 4 + ks2 * 2 + hi;
                int pc2 = (lc2 & 8) | ((lc2 ^ key7) & 7);
                tv[dg][ks2] = *(const bf16x8*)&gTw[(size_t)(dg * 32) * L_SEQ + pc2 * 8];
            }

        // S-GEMM (swapped): D[i=c][j=m], A = Cbf rows (this wave's 32 c).
        f32x16 s;
        #pragma unroll
        for (int r = 0; r < 16; ++r) s[r] = 0.0f;
        #pragma unroll
        for (int ks = 0; ks < 8; ++ks) {
            int lc = ks * 2 + hi;
            int pc = (lc & 8) | ((lc ^ key7) & 7);
            bf16x8 av = *(const bf16x8*)&gCw[pc * 8];
            s = __builtin_amdgcn_mfma_f32_32x32x16_bf16(av, mf[ks], s, 0, 0, 0);
        }

        // P = exp(S-40) -> bf16 pairs. Lane owns c_local = 8q + 4hi + {0..3}.
        unsigned u[4][2];
        #pragma unroll
        for (int q = 0; q < 4; ++q)
            #pragma unroll
            for (int jj = 0; jj < 2; ++jj) {
                float e0 = __expf(s[q * 4 + jj * 2]     - SHIFT);
                float e1 = __expf(s[q * 4 + jj * 2 + 1] - SHIFT);
                u[q][jj] = ((unsigned)(unsigned short)f2bf(e1) << 16)
                         |  (unsigned)(unsigned short)f2bf(e0);
            }

        // Half-wave exchange -> PV B-frags pa[ks2]: lane needs
        // c_local = ks2*16 + hi*8 + 0..7 of its column m = la.
        bf16x8 pa[2];
        #pragma unroll
        for (int ks2 = 0; ks2 < 2; ++ks2) {
            unsigned a0 = u[2 * ks2][0],     a1 = u[2 * ks2][1];
            unsigned b0 = u[2 * ks2 + 1][0], b1 = u[2 * ks2 + 1][1];
            unsigned a0p = (unsigned)__shfl_xor((int)a0, 32);
            unsigned a1p = (unsigned)__shfl_xor((int)a1, 32);
            unsigned b0p = (unsigned)__shfl_xor((int)b0, 32);
            unsigned b1p = (unsigned)__shfl_xor((int)b1, 32);
            uint4v pw;
            pw.x = hi ? b0p : a0;
            pw.y = hi ? b1p : a1;
            pw.z = hi ? b0  : a0p;
            pw.w = hi ? b1  : a1p;
            pa[ks2] = __builtin_bit_cast(bf16x8, pw);
        }

        // PV: D2[i=d][j=m], A = tv (CtL rows, K = c contiguous), B = pa.
        #pragma unroll
        for (int dg = 0; dg < 4; ++dg)
            #pragma unroll
            for (int ks2 = 0; ks2 < 2; ++ks2)
                o[dg] = __builtin_amdgcn_mfma_f32_32x32x16_bf16(tv[dg][ks2], pa[ks2], o[dg], 0, 0, 0);
    }

    // Epilogue: stage per-wave partials, sum the 4 c-slices, out = main - sum.
    {
        float* base = red[w];
        #pragma unroll
        for (int dg = 0; dg < 4; ++dg)
            #pragma unroll
            for (int r = 0; r < 16; ++r) {
                int d = dg * 32 + (r & 3) + 8 * (r >> 2) + 4 * hi;
                base[d * 32 + la] = o[dg][r];   // lanes la: consecutive banks
            }
    }
    __syncthreads();

    {
        int m  = t & 31;
        int dq = t >> 5;   // 0..7 : 16-d column block
        size_t gbase = ((size_t)(b * L_SEQ + mtile * 32 + m)) * DD + dq * 16;
        #pragma unroll
        for (int jq = 0; jq < 4; ++jq) {
            f32x4 v;
            #pragma unroll
            for (int e = 0; e < 4; ++e) {
                int idx = (dq * 16 + jq * 4 + e) * 32 + m;
                v[e] = red[0][idx] + red[1][idx] + red[2][idx] + red[3][idx];
            }
            f32x4 mv = *(const f32x4*)&mn[gbase + jq * 4];
            f32x4 ov;
            ov[0] = mv[0] - v[0]; ov[1] = mv[1] - v[1];
            ov[2] = mv[2] - v[2]; ov[3] = mv[3] - v[3];
            *(f32x4*)&out[gbase + jq * 4] = ov;
        }
    }
}

// ---------------------------------------------------------------------------
// Fallback path (round-2 kernels, tiny workspace)
// ---------------------------------------------------------------------------

__global__ __launch_bounds__(256, 4) void stats_fb(const float* __restrict__ ctx,
                                                   const float* __restrict__ mn,
                                                   float* __restrict__ Lg) {
    __shared__ short Cs[64 * LDA];
    __shared__ short Ms[64 * LDA];

    int bid = blockIdx.x;
    int mc = bid & 3;
    int ct = (bid >> 2) & 31;
    int b  = bid >> 7;
    int t = threadIdx.x;
    int w = t >> 6;
    int l = t & 63;
    int a15 = l & 15;
    int q = l >> 4;

    stage_tile<256>(Cs, ctx + ((size_t)b * L_SEQ + ct * 64) * DD, 64 * DD, t);

    float ls[4] = {0.f, 0.f, 0.f, 0.f};
    for (int mt = 0; mt < 8; ++mt) {
        __syncthreads();
        int m0 = (mc * 8 + mt) * 64;
        stage_tile<256>(Ms, mn + ((size_t)b * L_SEQ + m0) * DD, 64 * DD, t);
        __syncthreads();

        f32x4 acc[4] = {{0.f,0.f,0.f,0.f},{0.f,0.f,0.f,0.f},{0.f,0.f,0.f,0.f},{0.f,0.f,0.f,0.f}};
        #pragma unroll
        for (int ks = 0; ks < 4; ++ks) {
            int k0 = ks * 32 + q * 8;
            bf16x8 a = *(const bf16x8*)&Cs[(w * 16 + a15) * LDA + k0];
            #pragma unroll
            for (int g = 0; g < 4; ++g) {
                bf16x8 bb = *(const bf16x8*)&Ms[(g * 16 + a15) * LDA + k0];
                acc[g] = __builtin_amdgcn_mfma_f32_16x16x32_bf16(a, bb, acc[g], 0, 0, 0);
            }
        }
        #pragma unroll
        for (int g = 0; g < 4; ++g)
            #pragma unroll
            for (int r = 0; r < 4; ++r)
                ls[r] += __expf(acc[g][r] - SHIFT);
    }

    #pragma unroll
    for (int r = 0; r < 4; ++r) {
        float v = ls[r];
        v += __shfl_xor(v, 1);
        v += __shfl_xor(v, 2);
        v += __shfl_xor(v, 4);
        v += __shfl_xor(v, 8);
        ls[r] = v;
    }
    if (a15 == 0) {
        int c = ct * 64 + w * 16 + q * 4;
        #pragma unroll
        for (int r = 0; r < 4; ++r)
            atomicAdd(&Lg[(size_t)b * L_SEQ + c + r], ls[r]);
    }
}

__global__ __launch_bounds__(1024, 4) void attend_fb(const float* __restrict__ ctx,
                                                     const float* __restrict__ mn,
                                                     const float* __restrict__ Lg,
                                                     float* __restrict__ out) {
    __shared__ short Mt[64 * LDA];
    __shared__ short Cs[128 * LDA];
    __shared__ short Ct[128 * LDA];
    __shared__ short Ps[64 * LDA];
    __shared__ float invLs[128];

    int bid = blockIdx.x;
    int mtile = bid & 31;
    int b = bid >> 5;
    int m0 = mtile * 64;
    int t = threadIdx.x;
    int w = t >> 6;
    int l = t & 63;
    int a15 = l & 15;
    int q = l >> 4;
    int mg = w & 3;
    int pg = w >> 2;

    stage_tile<1024>(Mt, mn + ((size_t)b * L_SEQ + m0) * DD, 64 * DD, t);

    f32x4 oacc[2] = {{0.f,0.f,0.f,0.f},{0.f,0.f,0.f,0.f}};

    for (int cs = 0; cs < 16; ++cs) {
        int c0 = cs * 128;
        __syncthreads();
        stage_tile<1024>(Cs, ctx + ((size_t)b * L_SEQ + c0) * DD, 128 * DD, t);
        if (t < 128) invLs[t] = 1.0f / Lg[(size_t)b * L_SEQ + c0 + t];
        __syncthreads();

        {
            int cc = t & 127;
            int d0 = (t >> 7) * 16;
            #pragma unroll
            for (int hh = 0; hh < 2; ++hh) {
                bf16x8 v = *(const bf16x8*)&Cs[cc * LDA + d0 + hh * 8];
                #pragma unroll
                for (int j = 0; j < 8; ++j)
                    Ct[(d0 + hh * 8 + j) * LDA + cc] = v[j];
            }
        }

        f32x4 sacc[2] = {{0.f,0.f,0.f,0.f},{0.f,0.f,0.f,0.f}};
        #pragma unroll
        for (int ks = 0; ks < 4; ++ks) {
            int k0 = ks * 32 + q * 8;
            bf16x8 a = *(const bf16x8*)&Mt[(mg * 16 + a15) * LDA + k0];
            #pragma unroll
            for (int g = 0; g < 2; ++g) {
                bf16x8 bb = *(const bf16x8*)&Cs[((pg * 2 + g) * 16 + a15) * LDA + k0];
                sacc[g] = __builtin_amdgcn_mfma_f32_16x16x32_bf16(a, bb, sacc[g], 0, 0, 0);
            }
        }
        #pragma unroll
        for (int g = 0; g < 2; ++g) {
            int cl = (pg * 2 + g) * 16 + a15;
            float il = invLs[cl];
            #pragma unroll
            for (int r = 0; r < 4; ++r) {
                float p = __expf(sacc[g][r] - SHIFT) * il;
                Ps[(mg * 16 + q * 4 + r) * LDA + cl] = f2bf(p);
            }
        }
        __syncthreads();

        #pragma unroll
        for (int ks = 0; ks < 4; ++ks) {
            int k0 = ks * 32 + q * 8;
            bf16x8 a = *(const bf16x8*)&Ps[(mg * 16 + a15) * LDA + k0];
            #pragma unroll
            for (int g = 0; g < 2; ++g) {
                bf16x8 bb = *(const bf16x8*)&Ct[((pg * 2 + g) * 16 + a15) * LDA + k0];
                oacc[g] = __builtin_amdgcn_mfma_f32_16x16x32_bf16(a, bb, oacc[g], 0, 0, 0);
            }
        }
    }

    #pragma unroll
    for (int g = 0; g < 2; ++g) {
        int dl = (pg * 2 + g) * 16 + a15;
        #pragma unroll
        for (int r = 0; r < 4; ++r) {
            int ml = mg * 16 + q * 4 + r;
            size_t idx = ((size_t)b * L_SEQ + m0 + ml) * DD + dl;
            out[idx] = mn[idx] - oacc[g][r];
        }
    }
}

// ---------------------------------------------------------------------------

extern "C" void kernel_launch(void* const* d_in, const int* in_sizes, int n_in,
                              void* d_out, int out_size, void* d_ws, size_t ws_size,
                              hipStream_t stream) {
    const float* ctx = (const float*)d_in[0];  // (B, Lc, D)
    const float* mn  = (const float*)d_in[1];  // (B, Lm, D)
    float* out = (float*)d_out;                // (B, Lm, D)

    // Workspace: Lg 64 KB | Cbf 4 MB | Mbf 4 MB | CtL 4 MB   (E eliminated)
    const size_t LG_BYTES = (size_t)BATCH * L_SEQ * sizeof(float);
    const size_t BF_BYTES = (size_t)BATCH * L_SEQ * DD * sizeof(short);
    const size_t NEED = LG_BYTES + 3 * BF_BYTES;

    float* Lg = (float*)d_ws;

    if (ws_size >= NEED) {
        short* Cbf = (short*)((char*)d_ws + LG_BYTES);
        short* Mbf = (short*)((char*)d_ws + LG_BYTES + BF_BYTES);
        short* CtL = (short*)((char*)d_ws + LG_BYTES + 2 * BF_BYTES);
        convert_kernel<<<2048, 256, 0, stream>>>(ctx, mn, Cbf, Mbf, Lg);
        stats_kernel<<<BATCH * 16 * 4, 256, 0, stream>>>(Cbf, Mbf, Lg);
        prep_kernel<<<BATCH * 16, 256, 0, stream>>>(ctx, Lg, CtL);
        attend_fused<<<BATCH * 64, 256, 0, stream>>>(Cbf, Mbf, CtL, mn, out);
    } else {
        int nL = BATCH * L_SEQ;
        zero_kernel<<<(nL + 255) / 256, 256, 0, stream>>>(Lg, nL);
        stats_fb<<<BATCH * 32 * 4, 256, 0, stream>>>(ctx, mn, Lg);
        attend_fb<<<BATCH * 32, 1024, 0, stream>>>(ctx, mn, Lg, out);
    }
}

// Round 3
// 119.080 us; speedup vs baseline: 1.0487x; 1.0487x over previous
//
#include <hip/hip_runtime.h>

// AlignOnlySubLayer: out[b,m,d] = main[b,m,d] - sum_c softmax_m(C·M^T)[c,m] * C[c,d]
// B=8, Lc=Lm=2048, D=128, fp32 in/out.
// Round-11: counted-vmcnt pipelines (m201/m218 template). R10 showed direct
// global->reg fragments are transaction-bound (row-per-lane, 64 lines/wave-load,
// MfmaUtil 14%). Back to LDS staging (R9 mapping verbatim) but with raw
// s_barrier + inline s_waitcnt vmcnt(N) and 2-deep prefetch, so staging DMA
// never drains inside the loop. Applied to BOTH attend (vmcnt(8)/step) and
// stats (vmcnt(4)/step).
//   convert: Cbf/Mbf = bf16(ctx/main) swizzled; Lg = 0            (unchanged)
//   stats  : L[c] = sum_m exp(S-40), counted-vmcnt dbuf
//   prep   : CtL[b,d,c] = bf16(C[b,c,d]/L[b,c]) transposed+swizzled (unchanged)
//   attend_fused: 512 thr (2 mg x 4 ch), 128-c windows staged (Cs 32K + Ts 32K)
//     dbuf 128 KB; swapped S-MFMA -> exp/pack in-reg -> shfl_xor(32) PV B-frag
//     -> PV from Ts. Zero E traffic. 2-deep counted-vmcnt pipeline.
// Swizzle (all bf16 tensors): 16B chunk pc = (lc&8)|((lc^row)&7) within
// 64-elem groups; reads XOR the chunk index with row&7.

#define BATCH 8
#define L_SEQ 2048
#define DD 128
#define SHIFT 40.0f
#define LDA 136   // fallback/prep padded stride

typedef __attribute__((ext_vector_type(8))) short bf16x8;
typedef __attribute__((ext_vector_type(4))) short bf16x4;
typedef __attribute__((ext_vector_type(4))) float f32x4;
typedef __attribute__((ext_vector_type(16))) float f32x16;
typedef __attribute__((ext_vector_type(4))) unsigned int uint4v;

__device__ __forceinline__ short f2bf(float f) {
    unsigned u = __builtin_bit_cast(unsigned, f);
    return (short)((u + 0x8000u) >> 16);
}

// Async global->LDS, 16 B per lane. LDS dest = wave-uniform base + lane*16.
__device__ __forceinline__ void gl2lds16(const short* g, short* l) {
    __builtin_amdgcn_global_load_lds(
        (const __attribute__((address_space(1))) unsigned int*)g,
        (__attribute__((address_space(3))) unsigned int*)l, 16, 0, 0);
}

__device__ __forceinline__ void waitv8() { asm volatile("s_waitcnt vmcnt(8)" ::: "memory"); }
__device__ __forceinline__ void waitv4() { asm volatile("s_waitcnt vmcnt(4)" ::: "memory"); }
__device__ __forceinline__ void waitv0() { asm volatile("s_waitcnt vmcnt(0)" ::: "memory"); }

// fp32 global (rows of 128) -> bf16 LDS tile, stride LDA (fallback path only).
template <int NT>
__device__ __forceinline__ void stage_tile(short* __restrict__ dst,
                                           const float* __restrict__ src,
                                           int nelts, int t) {
    for (int base = 0; base < nelts; base += NT * 8) {
        int flat = base + t * 8;
        const float4* p = (const float4*)(src + flat);
        float4 v0 = p[0];
        float4 v1 = p[1];
        bf16x8 s;
        s[0] = f2bf(v0.x); s[1] = f2bf(v0.y); s[2] = f2bf(v0.z); s[3] = f2bf(v0.w);
        s[4] = f2bf(v1.x); s[5] = f2bf(v1.y); s[6] = f2bf(v1.z); s[7] = f2bf(v1.w);
        int row = flat >> 7;
        int col = flat & 127;
        *(bf16x8*)&dst[row * LDA + col] = s;
    }
}

__global__ __launch_bounds__(256) void zero_kernel(float* __restrict__ p, int n) {
    int i = blockIdx.x * 256 + threadIdx.x;
    if (i < n) p[i] = 0.0f;
}

// ---------------------------------------------------------------------------
// Fast path
// ---------------------------------------------------------------------------

// grid = 2048 x 256: one 16B chunk per thread for C and M; also zeros Lg.
__global__ __launch_bounds__(256) void convert_kernel(const float* __restrict__ ctx,
                                                      const float* __restrict__ mn,
                                                      short* __restrict__ Cbf,
                                                      short* __restrict__ Mbf,
                                                      float* __restrict__ Lg) {
    int tid = blockIdx.x * 256 + threadIdx.x;
    if (tid < BATCH * L_SEQ) Lg[tid] = 0.0f;
    const int half = BATCH * L_SEQ * DD / 8;  // chunks per tensor
    int id = tid;
    const float* src;
    short* dst;
    if (id < half) { src = ctx; dst = Cbf; }
    else           { id -= half; src = mn; dst = Mbf; }
    int row = id >> 4;
    int lc = id & 15;
    const float4* p = (const float4*)(src + ((size_t)row << 7) + lc * 8);
    float4 v0 = p[0];
    float4 v1 = p[1];
    bf16x8 s;
    s[0] = f2bf(v0.x); s[1] = f2bf(v0.y); s[2] = f2bf(v0.z); s[3] = f2bf(v0.w);
    s[4] = f2bf(v1.x); s[5] = f2bf(v1.y); s[6] = f2bf(v1.z); s[7] = f2bf(v1.w);
    int pc = (lc & 8) | ((lc ^ row) & 7);  // swizzle low 3 chunk bits by row&7
    *(bf16x8*)&dst[((size_t)row << 7) + pc * 8] = s;
}

// grid = 512 blocks (b = bid&7 for XCD batch affinity), 256 thr (4 waves).
// LDS: Cs 32 KB + Ms dbuf 2x16 KB = 64 KB -> 2 blocks/CU (8 waves/CU).
// Counted-vmcnt pipeline: Ms staged 2-deep, barriers never drain the DMA.
__global__ __launch_bounds__(256, 2) void stats_kernel(const short* __restrict__ Cbf,
                                                       const short* __restrict__ Mbf,
                                                       float* __restrict__ Lg) {
    __shared__ short Cs[128 * 128];
    __shared__ short Ms[2][64 * 128];

    int bid = blockIdx.x;
    int b  = bid & 7;          // XCD affinity: all blocks of batch b on one XCD
    int r2 = bid >> 3;
    int mc = r2 & 3;
    int ct = r2 >> 2;
    int t = threadIdx.x;
    int w = t >> 6;
    int l = t & 63;
    int a15 = l & 15;
    int q = l >> 4;
    int h = a15 & 7;
    int cw = (w & 1) * 64;   // wave c-offset within the 128-c tile
    int mw = (w >> 1) * 32;  // wave m-offset within the 64-m step

    const short* gC = Cbf + ((size_t)(b * L_SEQ + ct * 128)) * DD;
    const short* gM = Mbf + ((size_t)(b * L_SEQ + mc * 512)) * DD;

    {   // issue Cs (8 insts/wave) + Ms[0] + Ms[1] (4 insts/wave each)
        #pragma unroll
        for (int ii = 0; ii < 8; ++ii) {
            int inst = w * 8 + ii;
            gl2lds16(gC + inst * 512 + l * 8, Cs + inst * 512);
        }
        #pragma unroll
        for (int ii = 0; ii < 4; ++ii) {
            int inst = w * 4 + ii;
            gl2lds16(gM + inst * 512 + l * 8, Ms[0] + inst * 512);
        }
        #pragma unroll
        for (int ii = 0; ii < 4; ++ii) {
            int inst = w * 4 + ii;
            gl2lds16(gM + (size_t)64 * DD + inst * 512 + l * 8, Ms[1] + inst * 512);
        }
    }

    // Wait own Cs (8 newest = Ms[0]+Ms[1] may fly), publish via barrier.
    waitv8();
    __builtin_amdgcn_s_barrier();
    __builtin_amdgcn_sched_barrier(0);

    // Hoist invariant C A-fragments: af[ks][i], 16 ds_read_b128 -> 64 VGPRs.
    bf16x8 af[4][4];
    #pragma unroll
    for (int ks = 0; ks < 4; ++ks) {
        int aoff = ((ks * 4 + q) ^ h) * 8;
        #pragma unroll
        for (int i = 0; i < 4; ++i)
            af[ks][i] = *(const bf16x8*)&Cs[(cw + i * 16 + a15) * 128 + aoff];
    }

    float ls[4][4] = {};  // partial L for c = ct*128 + cw + i*16 + q*4 + r

    for (int ms = 0; ms < 8; ++ms) {
        int bp = ms & 1;
        // steady state: 4 insts of step ms+1 outstanding; drain only at the end
        if (ms < 7) waitv4(); else waitv0();
        __builtin_amdgcn_s_barrier();
        __builtin_amdgcn_sched_barrier(0);

        // D[c][m]: A = hoisted C frags (wave's 64 c), B = M rows (wave's 32 m).
        f32x4 acc[4][2];
        #pragma unroll
        for (int i = 0; i < 4; ++i)
            #pragma unroll
            for (int j = 0; j < 2; ++j) {
                f32x4 z = {0.f, 0.f, 0.f, 0.f};
                acc[i][j] = z;
            }
        #pragma unroll
        for (int ks = 0; ks < 4; ++ks) {
            int aoff = ((ks * 4 + q) ^ h) * 8;
            bf16x8 bv[2];
            #pragma unroll
            for (int j = 0; j < 2; ++j)
                bv[j] = *(const bf16x8*)&Ms[bp][(mw + j * 16 + a15) * 128 + aoff];
            #pragma unroll
            for (int i = 0; i < 4; ++i)
                #pragma unroll
                for (int j = 0; j < 2; ++j)
                    acc[i][j] = __builtin_amdgcn_mfma_f32_16x16x32_bf16(af[ks][i], bv[j], acc[i][j], 0, 0, 0);
        }

        #pragma unroll
        for (int j = 0; j < 2; ++j)
            #pragma unroll
            for (int i = 0; i < 4; ++i)
                #pragma unroll
                for (int r = 0; r < 4; ++r)
                    ls[i][r] += __expf(acc[i][j][r] - SHIFT);

        // all waves done reading Ms[bp] before overwriting it with step ms+2
        __builtin_amdgcn_s_barrier();
        __builtin_amdgcn_sched_barrier(0);
        if (ms + 2 < 8) {
            #pragma unroll
            for (int ii = 0; ii < 4; ++ii) {
                int inst = w * 4 + ii;
                gl2lds16(gM + (size_t)(ms + 2) * 64 * DD + inst * 512 + l * 8,
                         Ms[bp] + inst * 512);
            }
        }
    }

    // Reduce partial L over the 16 m-columns (lane bits 0..3), then atomics.
    #pragma unroll
    for (int i = 0; i < 4; ++i)
        #pragma unroll
        for (int r = 0; r < 4; ++r) {
            float v = ls[i][r];
            v += __shfl_xor(v, 1);
            v += __shfl_xor(v, 2);
            v += __shfl_xor(v, 4);
            v += __shfl_xor(v, 8);
            ls[i][r] = v;
        }
    if (a15 == 0) {
        #pragma unroll
        for (int i = 0; i < 4; ++i) {
            int c = ct * 128 + cw + i * 16 + q * 4;
            #pragma unroll
            for (int r = 0; r < 4; ++r)
                atomicAdd(&Lg[(size_t)b * L_SEQ + c + r], ls[i][r]);  // 8-way total contention
        }
    }
}

// grid = 8 b * 16 cc = 128 blocks, 256 thr. CtL[b][d][c] = bf16(C/L), swizzled by d&7.
__global__ __launch_bounds__(256) void prep_kernel(const float* __restrict__ ctx,
                                                   const float* __restrict__ Lg,
                                                   short* __restrict__ CtL) {
    __shared__ short Ts[128 * LDA];
    __shared__ float invLs[128];

    int b = blockIdx.x >> 4;
    int cc = blockIdx.x & 15;
    int t = threadIdx.x;

    if (t < 128) invLs[t] = 1.0f / Lg[(size_t)b * L_SEQ + cc * 128 + t];
    __syncthreads();

    const float* src = ctx + ((size_t)(b * L_SEQ + cc * 128)) * DD;
    #pragma unroll
    for (int i = 0; i < 8; ++i) {
        int flat = i * 2048 + t * 8;
        int r = flat >> 7;
        int c = flat & 127;
        const float4* p = (const float4*)(src + flat);
        float4 v0 = p[0];
        float4 v1 = p[1];
        float il = invLs[r];
        bf16x8 s;
        s[0] = f2bf(v0.x * il); s[1] = f2bf(v0.y * il); s[2] = f2bf(v0.z * il); s[3] = f2bf(v0.w * il);
        s[4] = f2bf(v1.x * il); s[5] = f2bf(v1.y * il); s[6] = f2bf(v1.z * il); s[7] = f2bf(v1.w * il);
        *(bf16x8*)&Ts[r * LDA + c] = s;
    }
    __syncthreads();

    int d = t >> 1;
    int ch = (t & 1) * 64;
    int key = d & 7;
    #pragma unroll
    for (int i = 0; i < 8; ++i) {
        int c = ch + i * 8;
        bf16x8 v;
        #pragma unroll
        for (int j = 0; j < 8; ++j) v[j] = Ts[(c + j) * LDA + d];
        int pc = cc * 16 + (ch >> 3) + (i ^ key);
        *(bf16x8*)&CtL[((size_t)(b * DD + d)) * L_SEQ + pc * 8] = v;
    }
}

// Fused recompute-attend, counted-vmcnt LDS pipeline.
// grid = 8 b * 32 mtiles(64 m) = 256 blocks (b = bid&7: XCD batch affinity),
// 512 thr = 8 waves = 2 mg x 4 ch. LDS 128 KB: dbuf { Cs 32K | Ts 32K } x 2;
// reused as float red[8][4096] for the cross-c-slice epilogue reduction.
// Per 128-c window: stage window+2 (8 insts/wave), wait vmcnt(8) (window's own
// staging done, next one in flight), barrier, S-MFMA from Cs + hoisted mf,
// exp+pack+shfl_xor(32) -> PV B-frag, PV from Ts, barrier, issue next stage.
__global__ __launch_bounds__(512, 2) void attend_fused(const short* __restrict__ Cbf,
                                                       const short* __restrict__ Mbf,
                                                       const short* __restrict__ CtL,
                                                       const float* __restrict__ mn,
                                                       float* __restrict__ out) {
    __shared__ __align__(16) char smem[131072];

    int bid = blockIdx.x;
    int b = bid & 7;           // XCD batch affinity (grid = 256, %8==0)
    int mtile = bid >> 3;      // 0..31, 64 m each
    int t = threadIdx.x;
    int w = t >> 6;            // 0..7
    int l = t & 63;
    int la = l & 31;
    int hi = l >> 5;
    int mg = w >> 2;           // 0,1 : m-group
    int ch = w & 3;            // 0..3: c-slice of the window

    int m_glob = mtile * 64 + mg * 32 + la;   // this lane's m (D col)
    int key7 = la & 7;

    // Hoist M B-fragments: mf[ks] covers d = ks*16 + hi*8 + e. One-time.
    bf16x8 mf[8];
    {
        const short* mrow = Mbf + ((size_t)(b * L_SEQ + m_glob)) * DD;
        #pragma unroll
        for (int ks = 0; ks < 8; ++ks) {
            int lc = ks * 2 + hi;
            int pc = (lc & 8) | ((lc ^ key7) & 7);
            mf[ks] = *(const bf16x8*)&mrow[pc * 8];
        }
    }

    auto stage = [&](int cs, int p) {
        short* Cw = (short*)(smem + p * 65536);
        short* Tw = (short*)(smem + p * 65536 + 32768);
        // Cs: 128 window rows of Cbf, contiguous -> 1 KB per inst, 32 insts.
        const short* gC = Cbf + ((size_t)(b * L_SEQ + cs * 128)) * DD;
        #pragma unroll
        for (int ii = 0; ii < 4; ++ii) {
            int inst = w * 4 + ii;
            gl2lds16(gC + inst * 512 + l * 8, Cw + inst * 512);
        }
        // Ts: 256 B window slice of each of 128 CtL d-rows -> 4 rows/inst.
        const short* gT = CtL + (size_t)b * DD * L_SEQ + (size_t)cs * 128;
        #pragma unroll
        for (int ii = 0; ii < 4; ++ii) {
            int inst = w * 4 + ii;
            int row = inst * 4 + (l >> 4);
            gl2lds16(gT + (size_t)row * L_SEQ + (l & 15) * 8, Tw + inst * 512);
        }
    };

    f32x16 o[4];
    #pragma unroll
    for (int dg = 0; dg < 4; ++dg)
        #pragma unroll
        for (int r = 0; r < 16; ++r) o[dg][r] = 0.0f;

    stage(0, 0);
    stage(1, 1);

    for (int cs = 0; cs < 16; ++cs) {
        int p = cs & 1;
        // own staging of window cs complete (8 newest = window cs+1 in flight)
        if (cs < 15) waitv8(); else waitv0();
        __builtin_amdgcn_s_barrier();     // all waves' window-cs staging published
        __builtin_amdgcn_sched_barrier(0);

        const short* Cw = (const short*)(smem + p * 65536);
        const short* Tw = (const short*)(smem + p * 65536 + 32768);

        // S-GEMM (swapped): D[i=c][j=m], A = Cs rows (this wave's 32 c).
        f32x16 s;
        #pragma unroll
        for (int r = 0; r < 16; ++r) s[r] = 0.0f;
        int crow = ch * 32 + la;
        #pragma unroll
        for (int ks = 0; ks < 8; ++ks) {
            int lc = ks * 2 + hi;
            int pc = (lc & 8) | ((lc ^ key7) & 7);
            bf16x8 av = *(const bf16x8*)&Cw[crow * 128 + pc * 8];
            s = __builtin_amdgcn_mfma_f32_32x32x16_bf16(av, mf[ks], s, 0, 0, 0);
        }

        // P = exp(S-40) -> bf16 pairs. Lane owns c_local = 8q + 4hi + {0..3}.
        unsigned u[4][2];
        #pragma unroll
        for (int q = 0; q < 4; ++q)
            #pragma unroll
            for (int jj = 0; jj < 2; ++jj) {
                float e0 = __expf(s[q * 4 + jj * 2]     - SHIFT);
                float e1 = __expf(s[q * 4 + jj * 2 + 1] - SHIFT);
                u[q][jj] = ((unsigned)(unsigned short)f2bf(e1) << 16)
                         |  (unsigned)(unsigned short)f2bf(e0);
            }

        // Half-wave exchange -> PV B-frags pa[ks2]: lane needs
        // c_local = ks2*16 + hi*8 + 0..7 of its column m = la.
        bf16x8 pa[2];
        #pragma unroll
        for (int ks2 = 0; ks2 < 2; ++ks2) {
            unsigned a0 = u[2 * ks2][0],     a1 = u[2 * ks2][1];
            unsigned b0 = u[2 * ks2 + 1][0], b1 = u[2 * ks2 + 1][1];
            unsigned a0p = (unsigned)__shfl_xor((int)a0, 32);
            unsigned a1p = (unsigned)__shfl_xor((int)a1, 32);
            unsigned b0p = (unsigned)__shfl_xor((int)b0, 32);
            unsigned b1p = (unsigned)__shfl_xor((int)b1, 32);
            uint4v pw;
            pw.x = hi ? b0p : a0;
            pw.y = hi ? b1p : a1;
            pw.z = hi ? b0  : a0p;
            pw.w = hi ? b1  : a1p;
            pa[ks2] = __builtin_bit_cast(bf16x8, pw);
        }

        // PV: D2[i=d][j=m], A = Ts rows (CtL d-rows, K = this wave's 32 c).
        #pragma unroll
        for (int dg = 0; dg < 4; ++dg) {
            int drow = dg * 32 + la;
            #pragma unroll
            for (int ks2 = 0; ks2 < 2; ++ks2) {
                int lc2 = ch * 4 + ks2 * 2 + hi;
                int pc2 = (lc2 & 8) | ((lc2 ^ key7) & 7);
                bf16x8 tv = *(const bf16x8*)&Tw[drow * 128 + pc2 * 8];
                o[dg] = __builtin_amdgcn_mfma_f32_32x32x16_bf16(tv, pa[ks2], o[dg], 0, 0, 0);
            }
        }

        // all waves done reading buf p before restaging it with window cs+2
        __builtin_amdgcn_s_barrier();
        __builtin_amdgcn_sched_barrier(0);
        if (cs + 2 < 16) stage(cs + 2, p);
    }

    // Epilogue: stage per-wave partials, sum the 4 c-slices, out = main - sum.
    __syncthreads();                      // nothing outstanding (waitv0 at cs=15)
    float* red = (float*)smem;            // red[wave][d*32 + m], 8 * 16 KB
    {
        float* base = red + w * 4096;
        #pragma unroll
        for (int dg = 0; dg < 4; ++dg)
            #pragma unroll
            for (int r = 0; r < 16; ++r) {
                int d = dg * 32 + (r & 3) + 8 * (r >> 2) + 4 * hi;
                base[d * 32 + la] = o[dg][r];   // lanes la: consecutive banks
            }
    }
    __syncthreads();

    {
        int mg2 = t >> 8;          // 0,1
        int dq  = (t >> 5) & 7;    // 0..7 : 16-d column block
        int m   = t & 31;
        int m_out = mtile * 64 + mg2 * 32 + m;
        size_t gbase = ((size_t)(b * L_SEQ + m_out)) * DD + dq * 16;
        const float* r0 = red + (mg2 * 4 + 0) * 4096;
        const float* r1 = red + (mg2 * 4 + 1) * 4096;
        const float* r2 = red + (mg2 * 4 + 2) * 4096;
        const float* r3 = red + (mg2 * 4 + 3) * 4096;
        #pragma unroll
        for (int jq = 0; jq < 4; ++jq) {
            f32x4 v;
            #pragma unroll
            for (int e = 0; e < 4; ++e) {
                int idx = (dq * 16 + jq * 4 + e) * 32 + m;
                v[e] = r0[idx] + r1[idx] + r2[idx] + r3[idx];
            }
            f32x4 mv = *(const f32x4*)&mn[gbase + jq * 4];
            f32x4 ov;
            ov[0] = mv[0] - v[0]; ov[1] = mv[1] - v[1];
            ov[2] = mv[2] - v[2]; ov[3] = mv[3] - v[3];
            *(f32x4*)&out[gbase + jq * 4] = ov;
        }
    }
}

// ---------------------------------------------------------------------------
// Fallback path (round-2 kernels, tiny workspace)
// ---------------------------------------------------------------------------

__global__ __launch_bounds__(256, 4) void stats_fb(const float* __restrict__ ctx,
                                                   const float* __restrict__ mn,
                                                   float* __restrict__ Lg) {
    __shared__ short Cs[64 * LDA];
    __shared__ short Ms[64 * LDA];

    int bid = blockIdx.x;
    int mc = bid & 3;
    int ct = (bid >> 2) & 31;
    int b  = bid >> 7;
    int t = threadIdx.x;
    int w = t >> 6;
    int l = t & 63;
    int a15 = l & 15;
    int q = l >> 4;

    stage_tile<256>(Cs, ctx + ((size_t)b * L_SEQ + ct * 64) * DD, 64 * DD, t);

    float ls[4] = {0.f, 0.f, 0.f, 0.f};
    for (int mt = 0; mt < 8; ++mt) {
        __syncthreads();
        int m0 = (mc * 8 + mt) * 64;
        stage_tile<256>(Ms, mn + ((size_t)b * L_SEQ + m0) * DD, 64 * DD, t);
        __syncthreads();

        f32x4 acc[4] = {{0.f,0.f,0.f,0.f},{0.f,0.f,0.f,0.f},{0.f,0.f,0.f,0.f},{0.f,0.f,0.f,0.f}};
        #pragma unroll
        for (int ks = 0; ks < 4; ++ks) {
            int k0 = ks * 32 + q * 8;
            bf16x8 a = *(const bf16x8*)&Cs[(w * 16 + a15) * LDA + k0];
            #pragma unroll
            for (int g = 0; g < 4; ++g) {
                bf16x8 bb = *(const bf16x8*)&Ms[(g * 16 + a15) * LDA + k0];
                acc[g] = __builtin_amdgcn_mfma_f32_16x16x32_bf16(a, bb, acc[g], 0, 0, 0);
            }
        }
        #pragma unroll
        for (int g = 0; g < 4; ++g)
            #pragma unroll
            for (int r = 0; r < 4; ++r)
                ls[r] += __expf(acc[g][r] - SHIFT);
    }

    #pragma unroll
    for (int r = 0; r < 4; ++r) {
        float v = ls[r];
        v += __shfl_xor(v, 1);
        v += __shfl_xor(v, 2);
        v += __shfl_xor(v, 4);
        v += __shfl_xor(v, 8);
        ls[r] = v;
    }
    if (a15 == 0) {
        int c = ct * 64 + w * 16 + q * 4;
        #pragma unroll
        for (int r = 0; r < 4; ++r)
            atomicAdd(&Lg[(size_t)b * L_SEQ + c + r], ls[r]);
    }
}

__global__ __launch_bounds__(1024, 4) void attend_fb(const float* __restrict__ ctx,
                                                     const float* __restrict__ mn,
                                                     const float* __restrict__ Lg,
                                                     float* __restrict__ out) {
    __shared__ short Mt[64 * LDA];
    __shared__ short Cs[128 * LDA];
    __shared__ short Ct[128 * LDA];
    __shared__ short Ps[64 * LDA];
    __shared__ float invLs[128];

    int bid = blockIdx.x;
    int mtile = bid & 31;
    int b = bid >> 5;
    int m0 = mtile * 64;
    int t = threadIdx.x;
    int w = t >> 6;
    int l = t & 63;
    int a15 = l & 15;
    int q = l >> 4;
    int mg = w & 3;
    int pg = w >> 2;

    stage_tile<1024>(Mt, mn + ((size_t)b * L_SEQ + m0) * DD, 64 * DD, t);

    f32x4 oacc[2] = {{0.f,0.f,0.f,0.f},{0.f,0.f,0.f,0.f}};

    for (int cs = 0; cs < 16; ++cs) {
        int c0 = cs * 128;
        __syncthreads();
        stage_tile<1024>(Cs, ctx + ((size_t)b * L_SEQ + c0) * DD, 128 * DD, t);
        if (t < 128) invLs[t] = 1.0f / Lg[(size_t)b * L_SEQ + c0 + t];
        __syncthreads();

        {
            int cc = t & 127;
            int d0 = (t >> 7) * 16;
            #pragma unroll
            for (int hh = 0; hh < 2; ++hh) {
                bf16x8 v = *(const bf16x8*)&Cs[cc * LDA + d0 + hh * 8];
                #pragma unroll
                for (int j = 0; j < 8; ++j)
                    Ct[(d0 + hh * 8 + j) * LDA + cc] = v[j];
            }
        }

        f32x4 sacc[2] = {{0.f,0.f,0.f,0.f},{0.f,0.f,0.f,0.f}};
        #pragma unroll
        for (int ks = 0; ks < 4; ++ks) {
            int k0 = ks * 32 + q * 8;
            bf16x8 a = *(const bf16x8*)&Mt[(mg * 16 + a15) * LDA + k0];
            #pragma unroll
            for (int g = 0; g < 2; ++g) {
                bf16x8 bb = *(const bf16x8*)&Cs[((pg * 2 + g) * 16 + a15) * LDA + k0];
                sacc[g] = __builtin_amdgcn_mfma_f32_16x16x32_bf16(a, bb, sacc[g], 0, 0, 0);
            }
        }
        #pragma unroll
        for (int g = 0; g < 2; ++g) {
            int cl = (pg * 2 + g) * 16 + a15;
            float il = invLs[cl];
            #pragma unroll
            for (int r = 0; r < 4; ++r) {
                float p = __expf(sacc[g][r] - SHIFT) * il;
                Ps[(mg * 16 + q * 4 + r) * LDA + cl] = f2bf(p);
            }
        }
        __syncthreads();

        #pragma unroll
        for (int ks = 0; ks < 4; ++ks) {
            int k0 = ks * 32 + q * 8;
            bf16x8 a = *(const bf16x8*)&Ps[(mg * 16 + a15) * LDA + k0];
            #pragma unroll
            for (int g = 0; g < 2; ++g) {
                bf16x8 bb = *(const bf16x8*)&Ct[((pg * 2 + g) * 16 + a15) * LDA + k0];
                oacc[g] = __builtin_amdgcn_mfma_f32_16x16x32_bf16(a, bb, oacc[g], 0, 0, 0);
            }
        }
    }

    #pragma unroll
    for (int g = 0; g < 2; ++g) {
        int dl = (pg * 2 + g) * 16 + a15;
        #pragma unroll
        for (int r = 0; r < 4; ++r) {
            int ml = mg * 16 + q * 4 + r;
            size_t idx = ((size_t)b * L_SEQ + m0 + ml) * DD + dl;
            out[idx] = mn[idx] - oacc[g][r];
        }
    }
}

// ---------------------------------------------------------------------------

extern "C" void kernel_launch(void* const* d_in, const int* in_sizes, int n_in,
                              void* d_out, int out_size, void* d_ws, size_t ws_size,
                              hipStream_t stream) {
    const float* ctx = (const float*)d_in[0];  // (B, Lc, D)
    const float* mn  = (const float*)d_in[1];  // (B, Lm, D)
    float* out = (float*)d_out;                // (B, Lm, D)

    // Workspace: Lg 64 KB | Cbf 4 MB | Mbf 4 MB | CtL 4 MB   (E eliminated)
    const size_t LG_BYTES = (size_t)BATCH * L_SEQ * sizeof(float);
    const size_t BF_BYTES = (size_t)BATCH * L_SEQ * DD * sizeof(short);
    const size_t NEED = LG_BYTES + 3 * BF_BYTES;

    float* Lg = (float*)d_ws;

    if (ws_size >= NEED) {
        short* Cbf = (short*)((char*)d_ws + LG_BYTES);
        short* Mbf = (short*)((char*)d_ws + LG_BYTES + BF_BYTES);
        short* CtL = (short*)((char*)d_ws + LG_BYTES + 2 * BF_BYTES);
        convert_kernel<<<2048, 256, 0, stream>>>(ctx, mn, Cbf, Mbf, Lg);
        stats_kernel<<<BATCH * 16 * 4, 256, 0, stream>>>(Cbf, Mbf, Lg);
        prep_kernel<<<BATCH * 16, 256, 0, stream>>>(ctx, Lg, CtL);
        attend_fused<<<BATCH * 32, 512, 0, stream>>>(Cbf, Mbf, CtL, mn, out);
    } else {
        int nL = BATCH * L_SEQ;
        zero_kernel<<<(nL + 255) / 256, 256, 0, stream>>>(Lg, nL);
        stats_fb<<<BATCH * 32 * 4, 256, 0, stream>>>(ctx, mn, Lg);
        attend_fb<<<BATCH * 32, 1024, 0, stream>>>(ctx, mn, Lg, out);
    }
}